// Round 1
// baseline (750.654 us; speedup 1.0000x reference)
//
#include <hip/hip_runtime.h>

#define IDIM 384
#define SDIM 2048
#define NCH  8
#define CHUNK 256

// workspace layout (float offsets)
#define WS_STATS 0                                  // [I][S][2]  (mu, rstd)
#define WS_QGP   (IDIM*SDIM*2)                      // [I][NCH][65] (qg partial + count)
#define WS_Q     (WS_QGP + IDIM*NCH*65)             // [I][64]   scaled q
#define WS_ATT   (WS_Q + IDIM*64)                   // [I][NCH][8][10] (m,l,ctx[8])
#define WS_CTX   (WS_ATT + IDIM*NCH*8*10)           // [I][64]

// ---------------- Kernel A: LN stats + q_global partials -------------------
__global__ __launch_bounds__(256) void kA(const float* __restrict__ m,
                                          const float* __restrict__ mask,
                                          const float* __restrict__ gamma,
                                          const float* __restrict__ beta,
                                          float* __restrict__ ws) {
    int bx = blockIdx.x;
    int i = bx >> 3, chk = bx & 7;
    int w = threadIdx.x >> 6, lane = threadIdx.x & 63;
    float ga = gamma[lane], be = beta[lane];
    float qgp = 0.f, cnt = 0.f;
    int s0 = chk * CHUNK + w * 64;
    float* stats = ws + WS_STATS;
    for (int r = 0; r < 64; ++r) {
        int s = s0 + r;
        float x = m[((size_t)s * IDIM + i) * 64 + lane];
        float sx = x, sxx = x * x;
        #pragma unroll
        for (int off = 1; off < 64; off <<= 1) {
            sx  += __shfl_xor(sx, off);
            sxx += __shfl_xor(sxx, off);
        }
        float mu  = sx * (1.f / 64.f);
        float var = sxx * (1.f / 64.f) - mu * mu;
        float rs  = rsqrtf(var + 1e-5f);
        float mn  = (x - mu) * rs * ga + be;
        float mk  = mask[s * IDIM + i];
        qgp += mk * mn;
        cnt += mk;
        if (lane == 0) {
            stats[((size_t)i * SDIM + s) * 2]     = mu;
            stats[((size_t)i * SDIM + s) * 2 + 1] = rs;
        }
    }
    __shared__ float red[4][65];
    red[w][lane] = qgp;
    if (lane == 0) red[w][64] = cnt;
    __syncthreads();
    if (threadIdx.x < 65) {
        float v = red[0][threadIdx.x] + red[1][threadIdx.x] +
                  red[2][threadIdx.x] + red[3][threadIdx.x];
        ws[WS_QGP + (i * NCH + chk) * 65 + threadIdx.x] = v;
    }
}

// ---------------- Kernel B: reduce q_global, compute q = (qg @ WqT)/sqrt(8) -
__global__ __launch_bounds__(64) void kB(const float* __restrict__ Wq,
                                         float* __restrict__ ws) {
    int i = blockIdx.x, l = threadIdx.x;
    float sum = 0.f, cnt = 0.f;
    #pragma unroll
    for (int c = 0; c < NCH; ++c) {
        sum += ws[WS_QGP + (i * NCH + c) * 65 + l];
        cnt += ws[WS_QGP + (i * NCH + c) * 65 + 64];
    }
    float denom = fmaxf(cnt, 1e-5f);
    __shared__ float qg[64];
    qg[l] = sum / denom;
    __syncthreads();
    float acc = 0.f;
    #pragma unroll 8
    for (int c = 0; c < 64; ++c) acc += qg[c] * Wq[l * 64 + c];
    ws[WS_Q + i * 64 + l] = acc * 0.35355339059327373f;  // fold in 1/sqrt(CH)
}

// ---------------- Kernel C: k/v + flash-softmax partials per chunk ---------
__global__ __launch_bounds__(256) void kC(const float* __restrict__ m,
                                          const float* __restrict__ mask,
                                          const float* __restrict__ gamma,
                                          const float* __restrict__ beta,
                                          const float* __restrict__ Wk,
                                          const float* __restrict__ Wv,
                                          float* __restrict__ ws) {
    int bx = blockIdx.x;
    int i = bx >> 3, chk = bx & 7;
    int tid = threadIdx.x;
    __shared__ float mnT[32 * 68];
    __shared__ float Wk_s[8 * 68], Wv_s[8 * 68];
    __shared__ float k_s[32 * 9], v_s[32 * 9];
    __shared__ float q_s[64];
    __shared__ float red[32 * 8 * 10];
    const float* stats = ws + WS_STATS;

    if (tid < 64) q_s[tid] = ws[WS_Q + i * 64 + tid];
    for (int idx = tid; idx < 512; idx += 256) {
        int r = idx >> 6, c = idx & 63;
        Wk_s[r * 68 + c] = Wk[idx];
        Wv_s[r * 68 + c] = Wv[idx];
    }

    int sr = tid >> 3;   // 0..31
    int lo = tid & 7;    // ch (phase 2) or h (phase 3)
    float m_run = -1e30f, l_run = 0.f, ctx[8];
    #pragma unroll
    for (int z = 0; z < 8; ++z) ctx[z] = 0.f;
    __syncthreads();

    for (int t = 0; t < 8; ++t) {
        int sbase = chk * CHUNK + t * 32;
        // stage m_norm tile (recompute LN from stored stats)
        for (int idx = tid; idx < 512; idx += 256) {
            int r = idx >> 4, c4 = idx & 15;
            int s = sbase + r;
            float4 x4 = *(const float4*)&m[((size_t)s * IDIM + i) * 64 + c4 * 4];
            float4 g4 = *(const float4*)&gamma[c4 * 4];
            float4 b4 = *(const float4*)&beta[c4 * 4];
            float2 st = *(const float2*)&stats[((size_t)i * SDIM + s) * 2];
            float4 mn;
            mn.x = (x4.x - st.x) * st.y * g4.x + b4.x;
            mn.y = (x4.y - st.x) * st.y * g4.y + b4.y;
            mn.z = (x4.z - st.x) * st.y * g4.z + b4.z;
            mn.w = (x4.w - st.x) * st.y * g4.w + b4.w;
            *(float4*)&mnT[r * 68 + c4 * 4] = mn;
        }
        __syncthreads();
        // k, v : [32 rows][8 ch]
        {
            float accK = 0.f, accV = 0.f;
            #pragma unroll
            for (int c4 = 0; c4 < 16; ++c4) {
                float4 a  = *(const float4*)&mnT[sr * 68 + c4 * 4];
                float4 wk = *(const float4*)&Wk_s[lo * 68 + c4 * 4];
                float4 wv = *(const float4*)&Wv_s[lo * 68 + c4 * 4];
                accK += a.x * wk.x + a.y * wk.y + a.z * wk.z + a.w * wk.w;
                accV += a.x * wv.x + a.y * wv.y + a.z * wv.z + a.w * wv.w;
            }
            k_s[sr * 9 + lo] = accK;
            v_s[sr * 9 + lo] = accV;
        }
        __syncthreads();
        // online softmax update: thread = (row sr, head lo)
        {
            float lg = 0.f;
            #pragma unroll
            for (int c = 0; c < 8; ++c) lg += q_s[lo * 8 + c] * k_s[sr * 9 + c];
            float mk = mask[(sbase + sr) * IDIM + i];
            lg = (mk > 0.f) ? lg : -1e9f;
            float mnew = fmaxf(m_run, lg);
            float al = expf(m_run - mnew);
            float p  = expf(lg - mnew);
            l_run = l_run * al + p;
            #pragma unroll
            for (int c = 0; c < 8; ++c) ctx[c] = ctx[c] * al + p * v_s[sr * 9 + c];
            m_run = mnew;
        }
        __syncthreads();
    }
    // merge the 32 row-threads per head
    int base = (sr * 8 + lo) * 10;
    red[base] = m_run; red[base + 1] = l_run;
    #pragma unroll
    for (int c = 0; c < 8; ++c) red[base + 2 + c] = ctx[c];
    __syncthreads();
    if (tid < 8) {
        int h = tid;
        float M = -1e30f;
        for (int r = 0; r < 32; ++r) M = fmaxf(M, red[(r * 8 + h) * 10]);
        float L = 0.f, CT[8];
        #pragma unroll
        for (int c = 0; c < 8; ++c) CT[c] = 0.f;
        for (int r = 0; r < 32; ++r) {
            float e = expf(red[(r * 8 + h) * 10] - M);
            L += red[(r * 8 + h) * 10 + 1] * e;
            for (int c = 0; c < 8; ++c) CT[c] += red[(r * 8 + h) * 10 + 2 + c] * e;
        }
        float* dst = ws + WS_ATT + ((i * NCH + chk) * 8 + h) * 10;
        dst[0] = M; dst[1] = L;
        for (int c = 0; c < 8; ++c) dst[2 + c] = CT[c];
    }
}

// ---------------- Kernel D: merge chunk partials -> ctx --------------------
__global__ __launch_bounds__(64) void kD(float* __restrict__ ws) {
    int i = blockIdx.x, l = threadIdx.x;
    int h = l >> 3, c2 = l & 7;
    float M = -1e30f;
    #pragma unroll
    for (int c = 0; c < NCH; ++c)
        M = fmaxf(M, ws[WS_ATT + ((i * NCH + c) * 8 + h) * 10]);
    float L = 0.f, CT = 0.f;
    #pragma unroll
    for (int c = 0; c < NCH; ++c) {
        const float* src = ws + WS_ATT + ((i * NCH + c) * 8 + h) * 10;
        float e = expf(src[0] - M);
        L += src[1] * e;
        CT += src[2 + c2] * e;
    }
    ws[WS_CTX + i * 64 + l] = CT / L;
}

// ---------------- Kernel E: g = sigmoid(mn@WgT+bg); out=(ctx*g)@WoT+bo -----
__global__ __launch_bounds__(256, 2) void kE(const float* __restrict__ m,
                                             const float* __restrict__ gamma,
                                             const float* __restrict__ beta,
                                             const float* __restrict__ Wg,
                                             const float* __restrict__ bg,
                                             const float* __restrict__ Wo,
                                             const float* __restrict__ bo,
                                             const float* __restrict__ ws,
                                             float* __restrict__ out) {
    int bx = blockIdx.x;
    int i = bx >> 4;        // 16 tiles of 128 rows per column
    int tile = bx & 15;
    int tid = threadIdx.x;
    int rg = tid >> 3;      // 0..31 ; rows rg+32k
    int jg = tid & 7;       // output-channel group (8 wide)
    __shared__ float mnT[128 * 68];     // m_norm tile, later reused for o tile
    __shared__ float WgT[64 * 68];      // [c][j]
    __shared__ float WoT[64 * 68];      // [j][cc]
    const float* stats = ws + WS_STATS;

    for (int idx = tid; idx < 4096; idx += 256) {
        int rr = idx >> 6, cc = idx & 63;
        WgT[cc * 68 + rr] = Wg[idx];    // Wg[j][c] -> WgT[c][j]
        WoT[cc * 68 + rr] = Wo[idx];    // Wo[cc][j] -> WoT[j][cc]
    }
    float my_ctx[8], my_bg[8], my_bo[8];
    #pragma unroll
    for (int jj = 0; jj < 8; ++jj) {
        my_ctx[jj] = ws[WS_CTX + i * 64 + jg * 8 + jj];
        my_bg[jj]  = bg[jg * 8 + jj];
        my_bo[jj]  = bo[jg * 8 + jj];
    }
    int s0 = tile * 128;
    // stage m_norm tile
    for (int idx = tid; idx < 2048; idx += 256) {
        int r = idx >> 4, c4 = idx & 15;
        int s = s0 + r;
        float4 x4 = *(const float4*)&m[((size_t)s * IDIM + i) * 64 + c4 * 4];
        float4 g4 = *(const float4*)&gamma[c4 * 4];
        float4 b4 = *(const float4*)&beta[c4 * 4];
        float2 st = *(const float2*)&stats[((size_t)i * SDIM + s) * 2];
        float4 mn;
        mn.x = (x4.x - st.x) * st.y * g4.x + b4.x;
        mn.y = (x4.y - st.x) * st.y * g4.y + b4.y;
        mn.z = (x4.z - st.x) * st.y * g4.z + b4.z;
        mn.w = (x4.w - st.x) * st.y * g4.w + b4.w;
        *(float4*)&mnT[r * 68 + c4 * 4] = mn;
    }
    __syncthreads();
    // GEMM1: z[4 rows][8 cols] = mn @ WgT
    float z[4][8];
    #pragma unroll
    for (int k = 0; k < 4; ++k)
        #pragma unroll
        for (int jj = 0; jj < 8; ++jj) z[k][jj] = 0.f;
    #pragma unroll 4
    for (int c4 = 0; c4 < 16; ++c4) {
        float a[4][4];
        #pragma unroll
        for (int k = 0; k < 4; ++k) {
            float4 t = *(const float4*)&mnT[(rg + 32 * k) * 68 + c4 * 4];
            a[k][0] = t.x; a[k][1] = t.y; a[k][2] = t.z; a[k][3] = t.w;
        }
        #pragma unroll
        for (int cc = 0; cc < 4; ++cc) {
            int c = c4 * 4 + cc;
            float4 bA = *(const float4*)&WgT[c * 68 + jg * 8];
            float4 bB = *(const float4*)&WgT[c * 68 + jg * 8 + 4];
            float bv[8] = {bA.x, bA.y, bA.z, bA.w, bB.x, bB.y, bB.z, bB.w};
            #pragma unroll
            for (int k = 0; k < 4; ++k) {
                float av = a[k][cc];
                #pragma unroll
                for (int jj = 0; jj < 8; ++jj) z[k][jj] += av * bv[jj];
            }
        }
    }
    __syncthreads();
    // o = ctx * sigmoid(z + bg) -> back into mnT
    #pragma unroll
    for (int k = 0; k < 4; ++k) {
        float ov[8];
        #pragma unroll
        for (int jj = 0; jj < 8; ++jj) {
            float zv = z[k][jj] + my_bg[jj];
            float sg = 1.f / (1.f + expf(-zv));
            ov[jj] = my_ctx[jj] * sg;
        }
        float4 o0 = {ov[0], ov[1], ov[2], ov[3]};
        float4 o1 = {ov[4], ov[5], ov[6], ov[7]};
        *(float4*)&mnT[(rg + 32 * k) * 68 + jg * 8]     = o0;
        *(float4*)&mnT[(rg + 32 * k) * 68 + jg * 8 + 4] = o1;
    }
    __syncthreads();
    // GEMM2: out[4 rows][8 cc] = o @ WoT
    float w2[4][8];
    #pragma unroll
    for (int k = 0; k < 4; ++k)
        #pragma unroll
        for (int jj = 0; jj < 8; ++jj) w2[k][jj] = 0.f;
    #pragma unroll 4
    for (int c4 = 0; c4 < 16; ++c4) {
        float a[4][4];
        #pragma unroll
        for (int k = 0; k < 4; ++k) {
            float4 t = *(const float4*)&mnT[(rg + 32 * k) * 68 + c4 * 4];
            a[k][0] = t.x; a[k][1] = t.y; a[k][2] = t.z; a[k][3] = t.w;
        }
        #pragma unroll
        for (int cc = 0; cc < 4; ++cc) {
            int j = c4 * 4 + cc;
            float4 bA = *(const float4*)&WoT[j * 68 + jg * 8];
            float4 bB = *(const float4*)&WoT[j * 68 + jg * 8 + 4];
            float bv[8] = {bA.x, bA.y, bA.z, bA.w, bB.x, bB.y, bB.z, bB.w};
            #pragma unroll
            for (int k = 0; k < 4; ++k) {
                float av = a[k][cc];
                #pragma unroll
                for (int jj = 0; jj < 8; ++jj) w2[k][jj] += av * bv[jj];
            }
        }
    }
    #pragma unroll
    for (int k = 0; k < 4; ++k) {
        int s = s0 + rg + 32 * k;
        float4 o0 = {w2[k][0] + my_bo[0], w2[k][1] + my_bo[1],
                     w2[k][2] + my_bo[2], w2[k][3] + my_bo[3]};
        float4 o1 = {w2[k][4] + my_bo[4], w2[k][5] + my_bo[5],
                     w2[k][6] + my_bo[6], w2[k][7] + my_bo[7]};
        *(float4*)&out[((size_t)s * IDIM + i) * 64 + jg * 8]     = o0;
        *(float4*)&out[((size_t)s * IDIM + i) * 64 + jg * 8 + 4] = o1;
    }
}

extern "C" void kernel_launch(void* const* d_in, const int* in_sizes, int n_in,
                              void* d_out, int out_size, void* d_ws, size_t ws_size,
                              hipStream_t stream) {
    const float* m    = (const float*)d_in[0];
    const float* mask = (const float*)d_in[1];
    const float* gam  = (const float*)d_in[2];
    const float* bet  = (const float*)d_in[3];
    const float* Wq   = (const float*)d_in[4];
    const float* Wk   = (const float*)d_in[5];
    const float* Wv   = (const float*)d_in[6];
    const float* Wg   = (const float*)d_in[7];
    const float* bg   = (const float*)d_in[8];
    const float* Wo   = (const float*)d_in[9];
    const float* bo   = (const float*)d_in[10];
    float* out = (float*)d_out;
    float* ws  = (float*)d_ws;
    (void)in_sizes; (void)n_in; (void)out_size; (void)ws_size;

    kA<<<IDIM * NCH, 256, 0, stream>>>(m, mask, gam, bet, ws);
    kB<<<IDIM, 64, 0, stream>>>(Wq, ws);
    kC<<<IDIM * NCH, 256, 0, stream>>>(m, mask, gam, bet, Wk, Wv, ws);
    kD<<<IDIM, 64, 0, stream>>>(ws);
    kE<<<IDIM * (SDIM / 128), 256, 0, stream>>>(m, gam, bet, Wg, bg, Wo, bo, ws, out);
}